// Round 2
// baseline (256.582 us; speedup 1.0000x reference)
//
#include <hip/hip_runtime.h>
#include <hip/hip_bf16.h>
#include <stdint.h>

// Problem: B=2, N=4096, C=512, H=4, D=128.  MemoryEfficientAttention forward.
// Pipeline: cast(f32->bf16) -> QKV GEMM (MFMA bf16) -> flash attention (MFMA
// bf16, fp32 softmax/accum) -> proj GEMM (MFMA bf16, f32 out).
constexpr int B_  = 2;
constexpr int N_  = 4096;
constexpr int C_  = 512;
constexpr int H_  = 4;
constexpr int D_  = 128;
constexpr int M_  = B_ * N_;     // 8192
constexpr int TC_ = 3 * C_;     // 1536
constexpr float SCALE_ = 0.08838834764831845f;  // 1/sqrt(128)

typedef __attribute__((ext_vector_type(8))) short short8;   // 8 bf16 = 4 VGPR
typedef __attribute__((ext_vector_type(4))) float f32x4;    // MFMA C/D

static __device__ __forceinline__ uint16_t f2bf(float f) {
    uint32_t u = __builtin_bit_cast(uint32_t, f);
    uint32_t r = (u + 0x7FFFu + ((u >> 16) & 1u)) >> 16;   // RNE
    return (uint16_t)r;
}

// ---------------------------------------------------------------------------
// Cast f32 -> bf16, vectorized 8 elems/thread-iter.
// ---------------------------------------------------------------------------
__global__ __launch_bounds__(256)
void cast_kernel(const float* __restrict__ src, uint16_t* __restrict__ dst, int n8)
{
    for (int i = blockIdx.x * blockDim.x + threadIdx.x; i < n8;
         i += gridDim.x * blockDim.x) {
        float4 a = reinterpret_cast<const float4*>(src)[2*i];
        float4 b = reinterpret_cast<const float4*>(src)[2*i+1];
        uint4 o;
        o.x = (uint32_t)f2bf(a.x) | ((uint32_t)f2bf(a.y) << 16);
        o.y = (uint32_t)f2bf(a.z) | ((uint32_t)f2bf(a.w) << 16);
        o.z = (uint32_t)f2bf(b.x) | ((uint32_t)f2bf(b.y) << 16);
        o.w = (uint32_t)f2bf(b.z) | ((uint32_t)f2bf(b.w) << 16);
        reinterpret_cast<uint4*>(dst)[i] = o;
    }
}

// ---------------------------------------------------------------------------
// QKV GEMM: Y[m][o] = sum_k xb[m][k]*wb[o][k] + bias[o]   (NT, both K-contig)
// 128x128 tile, BK=64, 4 waves (each 64x64 = 4x4 frags), mfma 16x16x32 bf16.
// LDS XOR-swizzle: phys_chunk = k ^ (row&7)  (16B chunks; 8 lanes/bank-quad).
// Epilogue: Q,K -> [B,H,N,D] bf16;  V -> TRANSPOSED [B,H,D,N] bf16.
// ---------------------------------------------------------------------------
__global__ __launch_bounds__(256, 2)
void gemm_qkv(const uint16_t* __restrict__ A,   // xb [8192][512]
              const uint16_t* __restrict__ Bw,  // wb [1536][512]
              const float* __restrict__ bias,   // [1536]
              uint16_t* __restrict__ Qb,
              uint16_t* __restrict__ Kb,
              uint16_t* __restrict__ Vt)
{
    __shared__ __align__(16) uint16_t As[128 * 64];
    __shared__ __align__(16) uint16_t Bs[128 * 64];

    const int tid  = threadIdx.x;
    const int lane = tid & 63;
    const int w    = tid >> 6;      // wave 0..3
    const int wr   = w >> 1, wc = w & 1;
    const int c    = lane & 15;     // frag col / row-in-frag
    const int g    = lane >> 4;     // k-group
    const int m0   = blockIdx.x * 128;
    const int o0   = blockIdx.y * 128;

    f32x4 acc[4][4];
    const f32x4 zf = {0.f, 0.f, 0.f, 0.f};
    #pragma unroll
    for (int i = 0; i < 4; ++i)
        #pragma unroll
        for (int j = 0; j < 4; ++j) acc[i][j] = zf;

    for (int kt = 0; kt < C_; kt += 64) {
        __syncthreads();
        #pragma unroll
        for (int it = 0; it < 4; ++it) {           // 1024 slots, 4/thread
            int s = tid + 256 * it;
            int row = s >> 3, k = s & 7;           // row 0..127, 16B chunk 0..7
            int4 va = *reinterpret_cast<const int4*>(A  + (size_t)(m0+row)*C_ + kt + 8*k);
            int4 vb = *reinterpret_cast<const int4*>(Bw + (size_t)(o0+row)*C_ + kt + 8*k);
            int p = k ^ (row & 7);
            *reinterpret_cast<int4*>(&As[row*64 + p*8]) = va;
            *reinterpret_cast<int4*>(&Bs[row*64 + p*8]) = vb;
        }
        __syncthreads();
        #pragma unroll
        for (int ks = 0; ks < 2; ++ks) {           // two K=32 steps
            const int kc = g + 4*ks;               // logical 16B chunk
            short8 af[4], bfr[4];
            #pragma unroll
            for (int mi = 0; mi < 4; ++mi) {
                int r = 64*wr + 16*mi + c;
                af[mi] = *reinterpret_cast<const short8*>(&As[r*64 + (kc ^ (r&7))*8]);
            }
            #pragma unroll
            for (int ni = 0; ni < 4; ++ni) {
                int r = 64*wc + 16*ni + c;
                bfr[ni] = *reinterpret_cast<const short8*>(&Bs[r*64 + (kc ^ (r&7))*8]);
            }
            #pragma unroll
            for (int mi = 0; mi < 4; ++mi)
                #pragma unroll
                for (int ni = 0; ni < 4; ++ni)
                    acc[mi][ni] = __builtin_amdgcn_mfma_f32_16x16x32_bf16(
                        af[mi], bfr[ni], acc[mi][ni], 0, 0, 0);
        }
    }

    // Epilogue. o-tile is 128-aligned -> sec (Q/K/V) and h are block-uniform.
    const int sec = o0 >> 9;
    const int h   = (o0 >> 7) & 3;
    #pragma unroll
    for (int ni = 0; ni < 4; ++ni) {
        const int o = o0 + 64*wc + 16*ni + c;
        const int d = o & 127;
        const float bv = bias[o];
        #pragma unroll
        for (int mi = 0; mi < 4; ++mi) {
            #pragma unroll
            for (int r = 0; r < 4; ++r) {
                const int m = m0 + 64*wr + 16*mi + 4*g + r;   // C row = 4g+r
                const int b = m >> 12;
                const int n = m & (N_ - 1);
                const uint16_t hv = f2bf(acc[mi][ni][r] + bv);
                if (sec == 0)
                    Qb[(((size_t)b*H_ + h)*N_ + n)*D_ + d] = hv;
                else if (sec == 1)
                    Kb[(((size_t)b*H_ + h)*N_ + n)*D_ + d] = hv;
                else
                    Vt[(((size_t)b*H_ + h)*D_ + d)*N_ + n] = hv;
            }
        }
    }
}

// ---------------------------------------------------------------------------
// Flash attention, MFMA bf16.  BQ=64 (4 waves x 16 q-rows), BKV=64.
// Swapped QK^T:  S^T = K·Q^T  (A=K natural, B=Q natural; C cols = q).
//   -> lane owns q = lane&15; kv spread over regs + lane-groups g.
// Softmax: in-lane over 16 vals + shfl_xor(16,32).  P -> per-wave LDS
// ([16][72] bf16, b64 writes), re-read as PV A-operand (b128).
// PV: O = P·V with B-op = V^T tile from the transposed global layout.
// Grid 1-D: bh = bid&7  ==> each XCD's L2 caches exactly one head's K/V.
// LDS: Qs 16K + Ks 16K + Vs 16K + Ps 9K = 57.3 KB -> 2 blocks/CU.
// ---------------------------------------------------------------------------
__global__ __launch_bounds__(256, 2)
void attn_kernel(const uint16_t* __restrict__ Qb,
                 const uint16_t* __restrict__ Kb,
                 const uint16_t* __restrict__ Vt,
                 uint16_t* __restrict__ ctx)     // [B,N,C] bf16, c = h*128+d
{
    __shared__ __align__(16) uint16_t Qs[64 * 128];
    __shared__ __align__(16) uint16_t Ks[64 * 128];
    __shared__ __align__(16) uint16_t Vs[128 * 64];   // [d][kv]
    __shared__ __align__(16) uint16_t Ps[4][16 * 72]; // per-wave, stride 72

    const int tid  = threadIdx.x;
    const int lane = tid & 63;
    const int w    = tid >> 6;
    const int c    = lane & 15;
    const int g    = lane >> 4;

    const int bid = blockIdx.x;
    const int bh  = bid & 7;          // XCD-affine head
    const int qt  = bid >> 3;         // q-tile 0..63
    const int b   = bh >> 2, h = bh & 3;

    const uint16_t* Qg = Qb + ((size_t)bh * N_ + qt * 64) * D_;
    const uint16_t* Kg = Kb + (size_t)bh * N_ * D_;
    const uint16_t* Vg = Vt + (size_t)bh * D_ * N_;

    // stage Q tile [64][128], swizzled
    #pragma unroll
    for (int it = 0; it < 4; ++it) {
        int s = tid + 256 * it;
        int row = s >> 4, k = s & 15;
        int4 v = *reinterpret_cast<const int4*>(Qg + (size_t)row * D_ + 8*k);
        *reinterpret_cast<int4*>(&Qs[row*128 + (k ^ (row & 7))*8]) = v;
    }

    float m_run = -1e30f, l_run = 0.f;
    f32x4 o_acc[8];
    const f32x4 zf = {0.f, 0.f, 0.f, 0.f};
    #pragma unroll
    for (int i = 0; i < 8; ++i) o_acc[i] = zf;

    for (int t = 0; t < N_ / 64; ++t) {
        __syncthreads();                       // prev iter done reading Ks/Vs
        #pragma unroll
        for (int it = 0; it < 4; ++it) {       // K tile [64][128]
            int s = tid + 256 * it;
            int row = s >> 4, k = s & 15;
            int4 v = *reinterpret_cast<const int4*>(Kg + ((size_t)(t*64 + row))*D_ + 8*k);
            *reinterpret_cast<int4*>(&Ks[row*128 + (k ^ (row & 7))*8]) = v;
        }
        #pragma unroll
        for (int it = 0; it < 4; ++it) {       // V^T tile [128][64]
            int s = tid + 256 * it;
            int row = s >> 3, k = s & 7;       // row = d, chunk over kv
            int4 v = *reinterpret_cast<const int4*>(Vg + (size_t)row*N_ + t*64 + 8*k);
            *reinterpret_cast<int4*>(&Vs[row*64 + (k ^ (row & 7))*8]) = v;
        }
        __syncthreads();

        // ---- S^T = K·Q^T : 4 kv-frags x 4 d-ksteps ----
        f32x4 sacc[4];
        #pragma unroll
        for (int f = 0; f < 4; ++f) sacc[f] = zf;
        #pragma unroll
        for (int ksd = 0; ksd < 4; ++ksd) {
            const int kc = g + 4*ksd;
            const int qr = 16*w + c;
            short8 bq = *reinterpret_cast<const short8*>(&Qs[qr*128 + (kc ^ (qr&7))*8]);
            #pragma unroll
            for (int f = 0; f < 4; ++f) {
                int kr = 16*f + c;
                short8 ak = *reinterpret_cast<const short8*>(&Ks[kr*128 + (kc ^ (kr&7))*8]);
                sacc[f] = __builtin_amdgcn_mfma_f32_16x16x32_bf16(ak, bq, sacc[f], 0,0,0);
            }
        }

        // ---- online softmax (q = c; kv = 16f + 4g + r) ----
        float mt = -1e30f;
        #pragma unroll
        for (int f = 0; f < 4; ++f)
            #pragma unroll
            for (int r = 0; r < 4; ++r) {
                sacc[f][r] *= SCALE_;
                mt = fmaxf(mt, sacc[f][r]);
            }
        mt = fmaxf(mt, __shfl_xor(mt, 16));
        mt = fmaxf(mt, __shfl_xor(mt, 32));
        const float mnew = fmaxf(m_run, mt);
        const float corr = __expf(m_run - mnew);
        m_run = mnew;

        float lt = 0.f;
        uint32_t pw[8];
        #pragma unroll
        for (int f = 0; f < 4; ++f) {
            float p0 = __expf(sacc[f][0] - mnew);
            float p1 = __expf(sacc[f][1] - mnew);
            float p2 = __expf(sacc[f][2] - mnew);
            float p3 = __expf(sacc[f][3] - mnew);
            lt += (p0 + p1) + (p2 + p3);
            pw[2*f]   = (uint32_t)f2bf(p0) | ((uint32_t)f2bf(p1) << 16);
            pw[2*f+1] = (uint32_t)f2bf(p2) | ((uint32_t)f2bf(p3) << 16);
        }
        lt += __shfl_xor(lt, 16);
        lt += __shfl_xor(lt, 32);
        l_run = l_run * corr + lt;

        // publish P (row q=c, kv chunk 16f+4g), per-wave region -> no barrier
        #pragma unroll
        for (int f = 0; f < 4; ++f)
            *reinterpret_cast<uint2*>(&Ps[w][c*72 + 16*f + 4*g]) =
                make_uint2(pw[2*f], pw[2*f+1]);

        // rescale O: its rows are q = 4g+r -> fetch corr via shfl
        float corr_q[4];
        #pragma unroll
        for (int r = 0; r < 4; ++r) corr_q[r] = __shfl(corr, 4*g + r);
        #pragma unroll
        for (int cf = 0; cf < 8; ++cf)
            #pragma unroll
            for (int r = 0; r < 4; ++r) o_acc[cf][r] *= corr_q[r];

        // ---- PV: O += P·V  (A = P from LDS, B = V^T tile) ----
        #pragma unroll
        for (int ksv = 0; ksv < 2; ++ksv) {
            short8 ap = *reinterpret_cast<const short8*>(&Ps[w][c*72 + 32*ksv + 8*g]);
            #pragma unroll
            for (int cf = 0; cf < 8; ++cf) {
                int vr = 16*cf + c;
                int kc = g + 4*ksv;
                short8 bv = *reinterpret_cast<const short8*>(&Vs[vr*64 + (kc ^ (vr&7))*8]);
                o_acc[cf] = __builtin_amdgcn_mfma_f32_16x16x32_bf16(ap, bv, o_acc[cf], 0,0,0);
            }
        }
    }

    // ---- epilogue: O /= l, write ctx bf16 ----
    const float inv = 1.f / l_run;            // valid for q = c
    float inv_q[4];
    #pragma unroll
    for (int r = 0; r < 4; ++r) inv_q[r] = __shfl(inv, 4*g + r);
    #pragma unroll
    for (int cf = 0; cf < 8; ++cf) {
        #pragma unroll
        for (int r = 0; r < 4; ++r) {
            const int q = 16*w + 4*g + r;
            const int n = qt*64 + q;
            const int d = 16*cf + c;
            ctx[((size_t)b*N_ + n)*C_ + h*D_ + d] = f2bf(o_acc[cf][r] * inv_q[r]);
        }
    }
}

// ---------------------------------------------------------------------------
// Proj GEMM: out[m][o] = sum_k ctx[m][k]*pwb[o][k] + bias[o], f32 out.
// ---------------------------------------------------------------------------
__global__ __launch_bounds__(256, 2)
void gemm_proj(const uint16_t* __restrict__ A,   // ctx [8192][512]
               const uint16_t* __restrict__ Bw,  // pwb [512][512]
               const float* __restrict__ bias,   // [512]
               float* __restrict__ out)          // [8192][512] f32
{
    __shared__ __align__(16) uint16_t As[128 * 64];
    __shared__ __align__(16) uint16_t Bs[128 * 64];

    const int tid  = threadIdx.x;
    const int lane = tid & 63;
    const int w    = tid >> 6;
    const int wr   = w >> 1, wc = w & 1;
    const int c    = lane & 15;
    const int g    = lane >> 4;
    const int m0   = blockIdx.x * 128;
    const int o0   = blockIdx.y * 128;

    f32x4 acc[4][4];
    const f32x4 zf = {0.f, 0.f, 0.f, 0.f};
    #pragma unroll
    for (int i = 0; i < 4; ++i)
        #pragma unroll
        for (int j = 0; j < 4; ++j) acc[i][j] = zf;

    for (int kt = 0; kt < C_; kt += 64) {
        __syncthreads();
        #pragma unroll
        for (int it = 0; it < 4; ++it) {
            int s = tid + 256 * it;
            int row = s >> 3, k = s & 7;
            int4 va = *reinterpret_cast<const int4*>(A  + (size_t)(m0+row)*C_ + kt + 8*k);
            int4 vb = *reinterpret_cast<const int4*>(Bw + (size_t)(o0+row)*C_ + kt + 8*k);
            int p = k ^ (row & 7);
            *reinterpret_cast<int4*>(&As[row*64 + p*8]) = va;
            *reinterpret_cast<int4*>(&Bs[row*64 + p*8]) = vb;
        }
        __syncthreads();
        #pragma unroll
        for (int ks = 0; ks < 2; ++ks) {
            const int kc = g + 4*ks;
            short8 af[4], bfr[4];
            #pragma unroll
            for (int mi = 0; mi < 4; ++mi) {
                int r = 64*wr + 16*mi + c;
                af[mi] = *reinterpret_cast<const short8*>(&As[r*64 + (kc ^ (r&7))*8]);
            }
            #pragma unroll
            for (int ni = 0; ni < 4; ++ni) {
                int r = 64*wc + 16*ni + c;
                bfr[ni] = *reinterpret_cast<const short8*>(&Bs[r*64 + (kc ^ (r&7))*8]);
            }
            #pragma unroll
            for (int mi = 0; mi < 4; ++mi)
                #pragma unroll
                for (int ni = 0; ni < 4; ++ni)
                    acc[mi][ni] = __builtin_amdgcn_mfma_f32_16x16x32_bf16(
                        af[mi], bfr[ni], acc[mi][ni], 0, 0, 0);
        }
    }

    #pragma unroll
    for (int ni = 0; ni < 4; ++ni) {
        const int o = o0 + 64*wc + 16*ni + c;
        const float bv = bias[o];
        #pragma unroll
        for (int mi = 0; mi < 4; ++mi) {
            #pragma unroll
            for (int r = 0; r < 4; ++r) {
                const int m = m0 + 64*wr + 16*mi + 4*g + r;
                out[(size_t)m * C_ + o] = acc[mi][ni][r] + bv;
            }
        }
    }
}

// ---------------------------------------------------------------------------
extern "C" void kernel_launch(void* const* d_in, const int* in_sizes, int n_in,
                              void* d_out, int out_size, void* d_ws, size_t ws_size,
                              hipStream_t stream)
{
    const float* x      = (const float*)d_in[0];
    const float* qkv_w  = (const float*)d_in[1];
    const float* qkv_b  = (const float*)d_in[2];
    const float* proj_w = (const float*)d_in[3];
    const float* proj_b = (const float*)d_in[4];
    float* out = (float*)d_out;

    // ws layout (bf16 elems): xb 4.19M | wb 786K | pwb 262K | Qb,Kb,Vt,ctx 4x4.19M
    uint16_t* xb  = (uint16_t*)d_ws;
    uint16_t* wb  = xb  + (size_t)M_ * C_;          // 4194304
    uint16_t* pwb = wb  + (size_t)TC_ * C_;         //  786432
    uint16_t* Qb  = pwb + (size_t)C_ * C_;          //  262144
    uint16_t* Kb  = Qb  + (size_t)M_ * D_ * H_ / H_ * 1;  // = 4194304 elems
    // (B*H*N*D == M_*C_/... keep it explicit:)
    // Qb/Kb/Vt/ctx each hold B_*H_*N_*D_ = 4194304 bf16.
    Kb = Qb + (size_t)B_*H_*N_*D_;
    uint16_t* Vt  = Kb + (size_t)B_*H_*N_*D_;
    uint16_t* ctx = Vt + (size_t)B_*H_*N_*D_;

    cast_kernel<<<1024, 256, 0, stream>>>(x,      xb,  M_*C_/8);
    cast_kernel<<< 384, 256, 0, stream>>>(qkv_w,  wb,  TC_*C_/8);
    cast_kernel<<< 128, 256, 0, stream>>>(proj_w, pwb, C_*C_/8);

    gemm_qkv<<<dim3(M_/128, TC_/128), 256, 0, stream>>>(xb, wb, qkv_b, Qb, Kb, Vt);
    attn_kernel<<<(N_/64) * (B_*H_), 256, 0, stream>>>(Qb, Kb, Vt, ctx);
    gemm_proj<<<dim3(M_/128, C_/128), 256, 0, stream>>>(ctx, pwb, proj_b, out);
}

// Round 4
// 229.987 us; speedup vs baseline: 1.1156x; 1.1156x over previous
//
#include <hip/hip_runtime.h>
#include <hip/hip_bf16.h>
#include <stdint.h>

// Problem: B=2, N=4096, C=512, H=4, D=128.  MemoryEfficientAttention forward.
// cast(f32->bf16) -> QKV GEMM (MFMA bf16, K pre-scaled) -> flash attention
// (MFMA bf16, exp2-domain softmax, O^T form) -> proj GEMM (f32 out).
constexpr int B_  = 2;
constexpr int N_  = 4096;
constexpr int C_  = 512;
constexpr int H_  = 4;
constexpr int D_  = 128;
constexpr int M_  = B_ * N_;     // 8192
constexpr int TC_ = 3 * C_;      // 1536
constexpr float SCALE_  = 0.08838834764831845f;   // 1/sqrt(128)
constexpr float LOG2E_  = 1.4426950408889634f;
constexpr float KSCALE_ = SCALE_ * LOG2E_;        // folded into K at production

typedef __attribute__((ext_vector_type(8))) short short8;   // 8 bf16 = 4 VGPR
typedef __attribute__((ext_vector_type(4))) float f32x4;    // MFMA C/D

#define GLOBAL_AS __attribute__((address_space(1)))
#define LDS_AS    __attribute__((address_space(3)))

// Direct global->LDS DMA, 16B/lane. LDS dest must be wave-uniform base + lane*16.
static __device__ __forceinline__ void load_lds16(const void* gp, void* lp) {
    __builtin_amdgcn_global_load_lds((const GLOBAL_AS void*)gp, (LDS_AS void*)lp,
                                     16, 0, 0);
}

static __device__ __forceinline__ uint16_t f2bf(float f) {
    uint32_t u = __builtin_bit_cast(uint32_t, f);
    uint32_t r = (u + 0x7FFFu + ((u >> 16) & 1u)) >> 16;   // RNE
    return (uint16_t)r;
}
static __device__ __forceinline__ uint32_t cvt_pk_bf16(float lo, float hi) {
    uint32_t r;
    asm("v_cvt_pk_bf16_f32 %0, %1, %2" : "=v"(r) : "v"(lo), "v"(hi));
    return r;   // low16 = bf16(lo), high16 = bf16(hi)
}
// exp2 via single v_exp_f32 (register-only asm: no scheduling hazard).
static __device__ __forceinline__ float exp2f_fast(float x) {
    float r;
    asm("v_exp_f32 %0, %1" : "=v"(r) : "v"(x));
    return r;
}

// ---------------------------------------------------------------------------
// Cast f32 -> bf16, 8 elems/thread-iter.
// ---------------------------------------------------------------------------
__global__ __launch_bounds__(256)
void cast_kernel(const float* __restrict__ src, uint16_t* __restrict__ dst, int n8)
{
    for (int i = blockIdx.x * blockDim.x + threadIdx.x; i < n8;
         i += gridDim.x * blockDim.x) {
        float4 a = reinterpret_cast<const float4*>(src)[2*i];
        float4 b = reinterpret_cast<const float4*>(src)[2*i+1];
        uint4 o;
        o.x = (uint32_t)f2bf(a.x) | ((uint32_t)f2bf(a.y) << 16);
        o.y = (uint32_t)f2bf(a.z) | ((uint32_t)f2bf(a.w) << 16);
        o.z = (uint32_t)f2bf(b.x) | ((uint32_t)f2bf(b.y) << 16);
        o.w = (uint32_t)f2bf(b.z) | ((uint32_t)f2bf(b.w) << 16);
        reinterpret_cast<uint4*>(dst)[i] = o;
    }
}

// ---------------------------------------------------------------------------
// QKV GEMM (NT): Y[m][o] = sum_k xb[m][k]*wb[o][k] + bias[o].
// 128x128 tile, BK=64, 4 waves, mfma 16x16x32 bf16.
// Staging: global_load_lds w16, linear LDS dest, source pre-swizzled
// (chunk c = p ^ (row&7)); reads apply the same XOR -> 2-way max (free).
// Epilogue: Q -> [B,H,N,D]; K -> [B,H,N,D] * KSCALE_; V -> [B,H,D,N] (transposed).
// ---------------------------------------------------------------------------
__global__ __launch_bounds__(256, 2)
void gemm_qkv(const uint16_t* __restrict__ A,   // xb [8192][512]
              const uint16_t* __restrict__ Bw,  // wb [1536][512]
              const float* __restrict__ bias,   // [1536]
              uint16_t* __restrict__ Qb,
              uint16_t* __restrict__ Kb,
              uint16_t* __restrict__ Vt)
{
    __shared__ __align__(16) uint16_t As[128 * 64];
    __shared__ __align__(16) uint16_t Bs[128 * 64];

    const int tid  = threadIdx.x;
    const int lane = tid & 63;
    const int w    = tid >> 6;
    const int wr   = w >> 1, wc = w & 1;
    const int cq   = lane & 15;
    const int g    = lane >> 4;
    const int m0   = blockIdx.x * 128;
    const int o0   = blockIdx.y * 128;

    f32x4 acc[4][4];
    const f32x4 zf = {0.f, 0.f, 0.f, 0.f};
    #pragma unroll
    for (int i = 0; i < 4; ++i)
        #pragma unroll
        for (int j = 0; j < 4; ++j) acc[i][j] = zf;

    for (int kt = 0; kt < C_; kt += 64) {
        __syncthreads();
        #pragma unroll
        for (int i = 0; i < 4; ++i) {            // 1024 16B slots per tile
            int s = tid + 256 * i;
            int row = s >> 3, p = s & 7, c = p ^ (row & 7);
            load_lds16(A  + (size_t)(m0 + row) * C_ + kt + c * 8, &As[row*64 + p*8]);
            load_lds16(Bw + (size_t)(o0 + row) * C_ + kt + c * 8, &Bs[row*64 + p*8]);
        }
        __syncthreads();                         // compiler drains vmcnt here
        #pragma unroll
        for (int ks = 0; ks < 2; ++ks) {
            short8 af[4], bfr[4];
            #pragma unroll
            for (int mi = 0; mi < 4; ++mi) {
                int r = 64*wr + 16*mi + cq;
                af[mi] = *reinterpret_cast<const short8*>(
                    &As[r*64 + (((g + 4*ks) ^ (r & 7)) * 8)]);
            }
            #pragma unroll
            for (int ni = 0; ni < 4; ++ni) {
                int r = 64*wc + 16*ni + cq;
                bfr[ni] = *reinterpret_cast<const short8*>(
                    &Bs[r*64 + (((g + 4*ks) ^ (r & 7)) * 8)]);
            }
            #pragma unroll
            for (int mi = 0; mi < 4; ++mi)
                #pragma unroll
                for (int ni = 0; ni < 4; ++ni)
                    acc[mi][ni] = __builtin_amdgcn_mfma_f32_16x16x32_bf16(
                        af[mi], bfr[ni], acc[mi][ni], 0, 0, 0);
        }
    }

    // Epilogue. o-tile is 128-aligned -> sec and h are block-uniform.
    const int sec = o0 >> 9;
    const int h   = (o0 >> 7) & 3;
    #pragma unroll
    for (int ni = 0; ni < 4; ++ni) {
        const int o = o0 + 64*wc + 16*ni + cq;
        const int d = o & 127;
        const float bv = bias[o];
        #pragma unroll
        for (int mi = 0; mi < 4; ++mi) {
            #pragma unroll
            for (int r = 0; r < 4; ++r) {
                const int m = m0 + 64*wr + 16*mi + 4*g + r;
                const int b = m >> 12;
                const int n = m & (N_ - 1);
                const float y = acc[mi][ni][r] + bv;
                if (sec == 0)
                    Qb[(((size_t)b*H_ + h)*N_ + n)*D_ + d] = f2bf(y);
                else if (sec == 1)
                    Kb[(((size_t)b*H_ + h)*N_ + n)*D_ + d] = f2bf(y * KSCALE_);
                else
                    Vt[(((size_t)b*H_ + h)*D_ + d)*N_ + n] = f2bf(y);
            }
        }
    }
}

// ---------------------------------------------------------------------------
// Flash attention.  BQ=128 (4 waves x 32 q), BKV=128, 16x16x32 MFMA.
// S^T = K·Q^T (Q in regs); softmax in exp2 domain (K pre-scaled), defer-max;
// PV as O^T = V^T·P^T so O^T cols = q = lane&15 -> in-lane rescale/divide.
// K/V tiles double-buffered in LDS via global_load_lds (pre-swizzled source,
// chunk c = p ^ (row&15): all frag reads conflict-free). 1 block/CU, 144 KB LDS.
// Grid: 256 blocks, bh = bid&7 -> each XCD's L2 holds one head's K/V (2 MB).
// ---------------------------------------------------------------------------
__global__ __launch_bounds__(256, 1)
void attn_kernel(const uint16_t* __restrict__ Qb,
                 const uint16_t* __restrict__ Kb,   // pre-scaled by KSCALE_
                 const uint16_t* __restrict__ Vt,   // [B,H,D,N]
                 uint16_t* __restrict__ ctx)        // [B,N,C] bf16, c = h*128+d
{
    __shared__ __align__(16) uint16_t Ks[2][128 * 128];  // 2 x 32 KB
    __shared__ __align__(16) uint16_t Vs[2][128 * 128];  // 2 x 32 KB  ([d][kv])
    __shared__ __align__(16) uint16_t Ps[4][16 * 128];   // per-wave P, 4 KB

    const int tid  = threadIdx.x;
    const int lane = tid & 63;
    const int w    = tid >> 6;
    const int cq   = lane & 15;
    const int g    = lane >> 4;

    const int bid = blockIdx.x;
    const int bh  = bid & 7;          // XCD-affine head
    const int qt  = bid >> 3;         // q-tile 0..31
    const int b   = bh >> 2, h = bh & 3;

    const uint16_t* Qg = Qb + ((size_t)bh * N_ + qt * 128 + w * 32) * D_;
    const uint16_t* Kg = Kb + (size_t)bh * N_ * D_;
    const uint16_t* Vg = Vt + (size_t)bh * D_ * N_;

    auto stage = [&](int tn, int bb) {
        const int kv0 = tn * 128;
        #pragma unroll
        for (int i = 0; i < 8; ++i) {            // K tile [kv=128][d=128]
            int s = tid + 256 * i;
            int row = s >> 4, p = s & 15, c = p ^ (row & 15);
            load_lds16(Kg + (size_t)(kv0 + row) * D_ + c * 8,
                       &Ks[bb][row * 128 + p * 8]);
        }
        #pragma unroll
        for (int i = 0; i < 8; ++i) {            // V^T tile [d=128][kv=128]
            int s = tid + 256 * i;
            int row = s >> 4, p = s & 15, c = p ^ (row & 15);
            load_lds16(Vg + (size_t)row * N_ + kv0 + c * 8,
                       &Vs[bb][row * 128 + p * 8]);
        }
    };

    stage(0, 0);

    // Q fragments, global -> regs (16B/lane each), held for the whole kernel.
    short8 qreg[2][4];
    #pragma unroll
    for (int qf = 0; qf < 2; ++qf) {
        const uint16_t* qrow = Qg + (size_t)(16 * qf + cq) * D_;
        #pragma unroll
        for (int ks = 0; ks < 4; ++ks)
            qreg[qf][ks] = *reinterpret_cast<const short8*>(qrow + 32*ks + 8*g);
    }

    float m_run[2] = {-3.0e38f, -3.0e38f};
    float l_run[2] = {0.f, 0.f};
    f32x4 o_acc[8][2];                // [df][qf], O^T: rows d, cols q
    const f32x4 zf = {0.f, 0.f, 0.f, 0.f};
    #pragma unroll
    for (int df = 0; df < 8; ++df) { o_acc[df][0] = zf; o_acc[df][1] = zf; }

    __syncthreads();                  // stage(0) landed (vmcnt drained) for all

    for (int t = 0; t < N_ / 128; ++t) {
        const int cur = t & 1;
        if (t + 1 < N_ / 128) stage(t + 1, cur ^ 1);   // issue early, land late

        // ---- S^T = K·Q^T ----
        f32x4 sacc[8][2];
        #pragma unroll
        for (int kvf = 0; kvf < 8; ++kvf) { sacc[kvf][0] = zf; sacc[kvf][1] = zf; }
        #pragma unroll
        for (int ks = 0; ks < 4; ++ks) {
            #pragma unroll
            for (int kvf = 0; kvf < 8; ++kvf) {
                const int row = 16 * kvf + cq;
                const short8 ak = *reinterpret_cast<const short8*>(
                    &Ks[cur][row * 128 + (((g + 4*ks) ^ cq) * 8)]);
                sacc[kvf][0] = __builtin_amdgcn_mfma_f32_16x16x32_bf16(
                    ak, qreg[0][ks], sacc[kvf][0], 0, 0, 0);
                sacc[kvf][1] = __builtin_amdgcn_mfma_f32_16x16x32_bf16(
                    ak, qreg[1][ks], sacc[kvf][1], 0, 0, 0);
            }
        }

        // ---- softmax (exp2 domain) + P pack/write + P-frag read, per qf ----
        short8 bp[2][4];
        #pragma unroll
        for (int qf = 0; qf < 2; ++qf) {
            float pmax = -3.0e38f;
            #pragma unroll
            for (int kvf = 0; kvf < 8; ++kvf)
                #pragma unroll
                for (int r = 0; r < 4; ++r)
                    pmax = fmaxf(pmax, sacc[kvf][qf][r]);
            pmax = fmaxf(pmax, __shfl_xor(pmax, 16));
            pmax = fmaxf(pmax, __shfl_xor(pmax, 32));

            if (__any(pmax > m_run[qf] + 8.f)) {       // defer-max, THR=8
                const float mnew = fmaxf(m_run[qf], pmax);
                const float corr = exp2f_fast(m_run[qf] - mnew);
                m_run[qf] = mnew;
                l_run[qf] *= corr;
                #pragma unroll
                for (int df = 0; df < 8; ++df)
                    #pragma unroll
                    for (int r = 0; r < 4; ++r)
                        o_acc[df][qf][r] *= corr;      // in-lane: cols = my q
            }

            float lsum = 0.f;
            #pragma unroll
            for (int kvf = 0; kvf < 8; ++kvf) {
                const float p0 = exp2f_fast(sacc[kvf][qf][0] - m_run[qf]);
                const float p1 = exp2f_fast(sacc[kvf][qf][1] - m_run[qf]);
                const float p2 = exp2f_fast(sacc[kvf][qf][2] - m_run[qf]);
                const float p3 = exp2f_fast(sacc[kvf][qf][3] - m_run[qf]);
                lsum += (p0 + p1) + (p2 + p3);
                const uint32_t w0 = cvt_pk_bf16(p0, p1);
                const uint32_t w1 = cvt_pk_bf16(p2, p3);
                const int cw = 2 * kvf + (g >> 1);     // 16B chunk of kv 16kvf+4g
                *reinterpret_cast<uint2*>(
                    &Ps[w][cq * 128 + ((cw ^ cq) * 8 + 4 * (g & 1))]) =
                    make_uint2(w0, w1);
            }
            lsum += __shfl_xor(lsum, 16);
            lsum += __shfl_xor(lsum, 32);
            l_run[qf] += lsum;

            #pragma unroll
            for (int ks = 0; ks < 4; ++ks)             // P^T B-frags -> regs
                bp[qf][ks] = *reinterpret_cast<const short8*>(
                    &Ps[w][cq * 128 + (((g + 4*ks) ^ cq) * 8)]);
        }

        // ---- O^T += V^T · P^T  (V-frag shared across both qf) ----
        #pragma unroll
        for (int ks = 0; ks < 4; ++ks) {
            #pragma unroll
            for (int df = 0; df < 8; ++df) {
                const int row = 16 * df + cq;
                const short8 av = *reinterpret_cast<const short8*>(
                    &Vs[cur][row * 128 + (((g + 4*ks) ^ cq) * 8)]);
                o_acc[df][0] = __builtin_amdgcn_mfma_f32_16x16x32_bf16(
                    av, bp[0][ks], o_acc[df][0], 0, 0, 0);
                o_acc[df][1] = __builtin_amdgcn_mfma_f32_16x16x32_bf16(
                    av, bp[1][ks], o_acc[df][1], 0, 0, 0);
            }
        }
        __syncthreads();   // next tile staged + everyone done with buf cur
    }

    // ---- epilogue: O^T cols = my q -> in-lane divide; scatter bf16 ----
    #pragma unroll
    for (int qf = 0; qf < 2; ++qf) {
        const float inv = 1.f / l_run[qf];
        const int n = qt * 128 + w * 32 + 16 * qf + cq;
        uint16_t* dst = ctx + ((size_t)b * N_ + n) * C_ + h * D_;
        #pragma unroll
        for (int df = 0; df < 8; ++df)
            #pragma unroll
            for (int r = 0; r < 4; ++r)
                dst[16 * df + 4 * g + r] = f2bf(o_acc[df][qf][r] * inv);
    }
}

// ---------------------------------------------------------------------------
// Proj GEMM: out = ctx @ proj_w^T + bias, f32 out. Same staging as gemm_qkv.
// ---------------------------------------------------------------------------
__global__ __launch_bounds__(256, 2)
void gemm_proj(const uint16_t* __restrict__ A,   // ctx [8192][512]
               const uint16_t* __restrict__ Bw,  // pwb [512][512]
               const float* __restrict__ bias,   // [512]
               float* __restrict__ out)          // [8192][512] f32
{
    __shared__ __align__(16) uint16_t As[128 * 64];
    __shared__ __align__(16) uint16_t Bs[128 * 64];

    const int tid  = threadIdx.x;
    const int lane = tid & 63;
    const int w    = tid >> 6;
    const int wr   = w >> 1, wc = w & 1;
    const int cq   = lane & 15;
    const int g    = lane >> 4;
    const int m0   = blockIdx.x * 128;
    const int o0   = blockIdx.y * 128;

    f32x4 acc[4][4];
    const f32x4 zf = {0.f, 0.f, 0.f, 0.f};
    #pragma unroll
    for (int i = 0; i < 4; ++i)
        #pragma unroll
        for (int j = 0; j < 4; ++j) acc[i][j] = zf;

    for (int kt = 0; kt < C_; kt += 64) {
        __syncthreads();
        #pragma unroll
        for (int i = 0; i < 4; ++i) {
            int s = tid + 256 * i;
            int row = s >> 3, p = s & 7, c = p ^ (row & 7);
            load_lds16(A  + (size_t)(m0 + row) * C_ + kt + c * 8, &As[row*64 + p*8]);
            load_lds16(Bw + (size_t)(o0 + row) * C_ + kt + c * 8, &Bs[row*64 + p*8]);
        }
        __syncthreads();
        #pragma unroll
        for (int ks = 0; ks < 2; ++ks) {
            short8 af[4], bfr[4];
            #pragma unroll
            for (int mi = 0; mi < 4; ++mi) {
                int r = 64*wr + 16*mi + cq;
                af[mi] = *reinterpret_cast<const short8*>(
                    &As[r*64 + (((g + 4*ks) ^ (r & 7)) * 8)]);
            }
            #pragma unroll
            for (int ni = 0; ni < 4; ++ni) {
                int r = 64*wc + 16*ni + cq;
                bfr[ni] = *reinterpret_cast<const short8*>(
                    &Bs[r*64 + (((g + 4*ks) ^ (r & 7)) * 8)]);
            }
            #pragma unroll
            for (int mi = 0; mi < 4; ++mi)
                #pragma unroll
                for (int ni = 0; ni < 4; ++ni)
                    acc[mi][ni] = __builtin_amdgcn_mfma_f32_16x16x32_bf16(
                        af[mi], bfr[ni], acc[mi][ni], 0, 0, 0);
        }
    }

    #pragma unroll
    for (int ni = 0; ni < 4; ++ni) {
        const int o = o0 + 64*wc + 16*ni + cq;
        const float bv = bias[o];
        #pragma unroll
        for (int mi = 0; mi < 4; ++mi) {
            #pragma unroll
            for (int r = 0; r < 4; ++r) {
                const int m = m0 + 64*wr + 16*mi + 4*g + r;
                out[(size_t)m * C_ + o] = acc[mi][ni][r] + bv;
            }
        }
    }
}

// ---------------------------------------------------------------------------
extern "C" void kernel_launch(void* const* d_in, const int* in_sizes, int n_in,
                              void* d_out, int out_size, void* d_ws, size_t ws_size,
                              hipStream_t stream)
{
    const float* x      = (const float*)d_in[0];
    const float* qkv_w  = (const float*)d_in[1];
    const float* qkv_b  = (const float*)d_in[2];
    const float* proj_w = (const float*)d_in[3];
    const float* proj_b = (const float*)d_in[4];
    float* out = (float*)d_out;

    // ws layout (bf16 elems): xb | wb | pwb | Qb | Kb | Vt | ctx
    uint16_t* xb  = (uint16_t*)d_ws;
    uint16_t* wb  = xb  + (size_t)M_ * C_;           // 4194304
    uint16_t* pwb = wb  + (size_t)TC_ * C_;          //  786432
    uint16_t* Qb  = pwb + (size_t)C_ * C_;           //  262144
    uint16_t* Kb  = Qb  + (size_t)B_ * H_ * N_ * D_; // 4194304 each
    uint16_t* Vt  = Kb  + (size_t)B_ * H_ * N_ * D_;
    uint16_t* ctx = Vt  + (size_t)B_ * H_ * N_ * D_;

    cast_kernel<<<1024, 256, 0, stream>>>(x,      xb,  M_*C_/8);
    cast_kernel<<< 384, 256, 0, stream>>>(qkv_w,  wb,  TC_*C_/8);
    cast_kernel<<< 128, 256, 0, stream>>>(proj_w, pwb, C_*C_/8);

    gemm_qkv<<<dim3(M_/128, TC_/128), 256, 0, stream>>>(xb, wb, qkv_b, Qb, Kb, Vt);
    attn_kernel<<<(N_/128) * (B_*H_), 256, 0, stream>>>(Qb, Kb, Vt, ctx);
    gemm_proj<<<dim3(M_/128, C_/128), 256, 0, stream>>>(ctx, pwb, proj_b, out);
}

// Round 7
// 195.976 us; speedup vs baseline: 1.3093x; 1.1735x over previous
//
#include <hip/hip_runtime.h>
#include <hip/hip_bf16.h>
#include <stdint.h>

// Problem: B=2, N=4096, C=512, H=4, D=128.  MemoryEfficientAttention forward.
// cast3(f32->bf16) -> QKV GEMM (MFMA bf16, K pre-scaled, V transposed via LDS
// bounce) -> flash attention (8 waves, kv-split, exp2 softmax, O^T form,
// LDS merge) -> proj GEMM (f32 out).
constexpr int B_  = 2;
constexpr int N_  = 4096;
constexpr int C_  = 512;
constexpr int H_  = 4;
constexpr int D_  = 128;
constexpr int M_  = B_ * N_;     // 8192
constexpr int TC_ = 3 * C_;      // 1536
constexpr float SCALE_  = 0.08838834764831845f;   // 1/sqrt(128)
constexpr float LOG2E_  = 1.4426950408889634f;
constexpr float KSCALE_ = SCALE_ * LOG2E_;        // folded into K at production

typedef __attribute__((ext_vector_type(8))) short short8;   // 8 bf16 = 4 VGPR
typedef __attribute__((ext_vector_type(4))) float f32x4;    // MFMA C/D

#define GLOBAL_AS __attribute__((address_space(1)))
#define LDS_AS    __attribute__((address_space(3)))

// Direct global->LDS DMA, 16B/lane. LDS dest must be wave-uniform base + lane*16.
static __device__ __forceinline__ void load_lds16(const void* gp, void* lp) {
    __builtin_amdgcn_global_load_lds((const GLOBAL_AS void*)gp, (LDS_AS void*)lp,
                                     16, 0, 0);
}

static __device__ __forceinline__ uint16_t f2bf(float f) {
    uint32_t u = __builtin_bit_cast(uint32_t, f);
    uint32_t r = (u + 0x7FFFu + ((u >> 16) & 1u)) >> 16;   // RNE
    return (uint16_t)r;
}
static __device__ __forceinline__ uint32_t cvt_pk_bf16(float lo, float hi) {
    uint32_t r;
    asm("v_cvt_pk_bf16_f32 %0, %1, %2" : "=v"(r) : "v"(lo), "v"(hi));
    return r;   // low16 = bf16(lo), high16 = bf16(hi)
}
// exp2 via single v_exp_f32 (register-only asm: no scheduling hazard).
static __device__ __forceinline__ float exp2f_fast(float x) {
    float r;
    asm("v_exp_f32 %0, %1" : "=v"(r) : "v"(x));
    return r;
}

// ---------------------------------------------------------------------------
// Fused cast f32 -> bf16 for x, qkv_w, proj_w.  One block = 2048 elems.
// Grid 2560 = 2048 (x) + 384 (w) + 128 (pw), exact coverage.
// ---------------------------------------------------------------------------
__global__ __launch_bounds__(256)
void cast3_kernel(const float* __restrict__ x,  const float* __restrict__ w,
                  const float* __restrict__ pw,
                  uint16_t* __restrict__ xb, uint16_t* __restrict__ wb,
                  uint16_t* __restrict__ pwb)
{
    const int bid = blockIdx.x;
    const float* src; uint16_t* dst; int i;
    if (bid < 2048)      { src = x;  dst = xb;  i = bid * 256 + threadIdx.x; }
    else if (bid < 2432) { src = w;  dst = wb;  i = (bid - 2048) * 256 + threadIdx.x; }
    else                 { src = pw; dst = pwb; i = (bid - 2432) * 256 + threadIdx.x; }
    float4 a = reinterpret_cast<const float4*>(src)[2*i];
    float4 b = reinterpret_cast<const float4*>(src)[2*i+1];
    uint4 o;
    o.x = (uint32_t)f2bf(a.x) | ((uint32_t)f2bf(a.y) << 16);
    o.y = (uint32_t)f2bf(a.z) | ((uint32_t)f2bf(a.w) << 16);
    o.z = (uint32_t)f2bf(b.x) | ((uint32_t)f2bf(b.y) << 16);
    o.w = (uint32_t)f2bf(b.z) | ((uint32_t)f2bf(b.w) << 16);
    reinterpret_cast<uint4*>(dst)[i] = o;
}

// ---------------------------------------------------------------------------
// QKV GEMM (NT): Y[m][o] = sum_k xb[m][k]*wb[o][k] + bias[o].
// 128x128 tile, BK=64, 4 waves, mfma 16x16x32 bf16, global_load_lds staging.
// Epilogue: Q -> [B,H,N,D]; K -> same * KSCALE_; V -> [B,H,D,N] via LDS-bounce
// transpose (coalesced int4 stores).
// ---------------------------------------------------------------------------
__global__ __launch_bounds__(256, 2)
void gemm_qkv(const uint16_t* __restrict__ A,   // xb [8192][512]
              const uint16_t* __restrict__ Bw,  // wb [1536][512]
              const float* __restrict__ bias,   // [1536]
              uint16_t* __restrict__ Qb,
              uint16_t* __restrict__ Kb,
              uint16_t* __restrict__ Vt)
{
    __shared__ __align__(16) uint16_t SMEM[128 * 128];   // As | Bs, reused as T
    uint16_t* As = SMEM;                // [128][64]
    uint16_t* Bs = SMEM + 128 * 64;     // [128][64]

    const int tid  = threadIdx.x;
    const int lane = tid & 63;
    const int w    = tid >> 6;
    const int wr   = w >> 1, wc = w & 1;
    const int cq   = lane & 15;
    const int g    = lane >> 4;
    const int m0   = blockIdx.x * 128;
    const int o0   = blockIdx.y * 128;

    f32x4 acc[4][4];
    const f32x4 zf = {0.f, 0.f, 0.f, 0.f};
    #pragma unroll
    for (int i = 0; i < 4; ++i)
        #pragma unroll
        for (int j = 0; j < 4; ++j) acc[i][j] = zf;

    for (int kt = 0; kt < C_; kt += 64) {
        __syncthreads();
        #pragma unroll
        for (int i = 0; i < 4; ++i) {            // 1024 16B slots per tile
            int s = tid + 256 * i;
            int row = s >> 3, p = s & 7, c = p ^ (row & 7);
            load_lds16(A  + (size_t)(m0 + row) * C_ + kt + c * 8, &As[row*64 + p*8]);
            load_lds16(Bw + (size_t)(o0 + row) * C_ + kt + c * 8, &Bs[row*64 + p*8]);
        }
        __syncthreads();                         // compiler drains vmcnt here
        #pragma unroll
        for (int ks = 0; ks < 2; ++ks) {
            short8 af[4], bfr[4];
            #pragma unroll
            for (int mi = 0; mi < 4; ++mi) {
                int r = 64*wr + 16*mi + cq;
                af[mi] = *reinterpret_cast<const short8*>(
                    &As[r*64 + (((g + 4*ks) ^ (r & 7)) * 8)]);
            }
            #pragma unroll
            for (int ni = 0; ni < 4; ++ni) {
                int r = 64*wc + 16*ni + cq;
                bfr[ni] = *reinterpret_cast<const short8*>(
                    &Bs[r*64 + (((g + 4*ks) ^ (r & 7)) * 8)]);
            }
            #pragma unroll
            for (int mi = 0; mi < 4; ++mi)
                #pragma unroll
                for (int ni = 0; ni < 4; ++ni)
                    acc[mi][ni] = __builtin_amdgcn_mfma_f32_16x16x32_bf16(
                        af[mi], bfr[ni], acc[mi][ni], 0, 0, 0);
        }
    }

    // Epilogue. o-tile is 128-aligned -> sec and h are block-uniform.
    const int sec = o0 >> 9;
    const int h   = (o0 >> 7) & 3;
    if (sec < 2) {
        // Q / K: direct stores, [B,H,N,D]
        #pragma unroll
        for (int ni = 0; ni < 4; ++ni) {
            const int o = o0 + 64*wc + 16*ni + cq;
            const int d = o & 127;
            const float bv = bias[o];
            #pragma unroll
            for (int mi = 0; mi < 4; ++mi) {
                #pragma unroll
                for (int r = 0; r < 4; ++r) {
                    const int m = m0 + 64*wr + 16*mi + 4*g + r;
                    const int b = m >> 12;
                    const int n = m & (N_ - 1);
                    const float y = acc[mi][ni][r] + bv;
                    if (sec == 0)
                        Qb[(((size_t)b*H_ + h)*N_ + n)*D_ + d] = f2bf(y);
                    else
                        Kb[(((size_t)b*H_ + h)*N_ + n)*D_ + d] = f2bf(y * KSCALE_);
                }
            }
        }
    } else {
        // V: bounce acc through LDS (T[o_local=128][m_local=128]) -> coalesced
        // transposed stores to Vt [B,H,D,N].
        __syncthreads();                 // all compute reads of As/Bs done
        uint16_t* T = SMEM;              // [128][128]
        #pragma unroll
        for (int ni = 0; ni < 4; ++ni) {
            const int ol = 64*wc + 16*ni + cq;
            const float bv = bias[o0 + ol];
            #pragma unroll
            for (int mi = 0; mi < 4; ++mi) {
                const int ml = 64*wr + 16*mi + 4*g;
                const uint32_t w0 = (uint32_t)f2bf(acc[mi][ni][0] + bv)
                                  | ((uint32_t)f2bf(acc[mi][ni][1] + bv) << 16);
                const uint32_t w1 = (uint32_t)f2bf(acc[mi][ni][2] + bv)
                                  | ((uint32_t)f2bf(acc[mi][ni][3] + bv) << 16);
                *reinterpret_cast<uint2*>(&T[ol*128 + ml]) = make_uint2(w0, w1);
            }
        }
        __syncthreads();
        const int b = m0 >> 12;          // m-range never crosses batch boundary
        #pragma unroll
        for (int i = 0; i < 8; ++i) {    // 128 o-rows x 16 m-chunks
            int s = tid + 256 * i;
            int ro = s >> 4, mc = s & 15;
            int4 v = *reinterpret_cast<const int4*>(&T[ro*128 + mc*8]);
            const int n = (m0 & (N_ - 1)) + mc*8;
            *reinterpret_cast<int4*>(
                &Vt[(((size_t)b*H_ + h)*D_ + ro)*N_ + n]) = v;
        }
    }
}

// ---------------------------------------------------------------------------
// Flash attention.  512 threads = 8 waves.  BQ=128, BKV=128.
// Wave w: q-block (w&3) of 32 q-rows, kv-half (w>>2) of 64 kv rows.
// Independent online softmax per wave (exp2 domain, K pre-scaled, defer-max);
// O^T = V^T·P^T so O^T cols = q = lane&15 -> in-lane rescale.  Halves merged
// at epilogue via LDS (standard flash merge).  K/V double-buffered via
// global_load_lds with pre-swizzled source (chunk ^= row&15).
// LDS: Ks 64K + Vs 64K + Ps 20K = 148 KB -> 1 block/CU, 2 waves/SIMD.
// Grid: 256 blocks, bh = bid&7 -> each XCD's L2 holds one head's K/V.
// ---------------------------------------------------------------------------
__global__ __launch_bounds__(512, 1)
void attn_kernel(const uint16_t* __restrict__ Qb,
                 const uint16_t* __restrict__ Kb,   // pre-scaled by KSCALE_
                 const uint16_t* __restrict__ Vt,   // [B,H,D,N]
                 uint16_t* __restrict__ ctx)        // [B,N,C] bf16, c = h*128+d
{
    __shared__ __align__(16) uint16_t Ks[2][128 * 128];  // 2 x 32 KB
    __shared__ __align__(16) uint16_t Vs[2][128 * 128];  // 2 x 32 KB  ([d][kv])
    __shared__ __align__(16) uint16_t Ps[8][16 * 80];    // per-wave P [16 q][64 kv]

    const int tid  = threadIdx.x;
    const int lane = tid & 63;
    const int w    = tid >> 6;      // 0..7
    const int qb   = w & 3;         // q-block
    const int kvh  = w >> 2;        // kv half
    const int cq   = lane & 15;
    const int g    = lane >> 4;

    const int bid = blockIdx.x;
    const int bh  = bid & 7;        // XCD-affine head
    const int qt  = bid >> 3;       // q-tile 0..31
    const int b   = bh >> 2, h = bh & 3;

    const uint16_t* Qg = Qb + ((size_t)bh * N_ + qt * 128 + qb * 32) * D_;
    const uint16_t* Kg = Kb + (size_t)bh * N_ * D_;
    const uint16_t* Vg = Vt + (size_t)bh * D_ * N_;

    auto stage = [&](int tn, int bb) {
        const int kv0 = tn * 128;
        #pragma unroll
        for (int i = 0; i < 4; ++i) {            // K tile [kv=128][d=128]
            int s = tid + 512 * i;
            int row = s >> 4, p = s & 15, c = p ^ (row & 15);
            load_lds16(Kg + (size_t)(kv0 + row) * D_ + c * 8,
                       &Ks[bb][row * 128 + p * 8]);
        }
        #pragma unroll
        for (int i = 0; i < 4; ++i) {            // V^T tile [d=128][kv=128]
            int s = tid + 512 * i;
            int row = s >> 4, p = s & 15, c = p ^ (row & 15);
            load_lds16(Vg + (size_t)row * N_ + kv0 + c * 8,
                       &Vs[bb][row * 128 + p * 8]);
        }
    };

    stage(0, 0);

    // Q fragments, global -> regs, held for the whole kernel.
    short8 qreg[2][4];
    #pragma unroll
    for (int qf = 0; qf < 2; ++qf) {
        const uint16_t* qrow = Qg + (size_t)(16 * qf + cq) * D_;
        #pragma unroll
        for (int ks = 0; ks < 4; ++ks)
            qreg[qf][ks] = *reinterpret_cast<const short8*>(qrow + 32*ks + 8*g);
    }

    float m_run[2] = {-3.0e38f, -3.0e38f};
    float l_run[2] = {0.f, 0.f};
    f32x4 o_acc[8][2];                // [df][qf], O^T partial: rows d, cols q
    const f32x4 zf = {0.f, 0.f, 0.f, 0.f};
    #pragma unroll
    for (int df = 0; df < 8; ++df) { o_acc[df][0] = zf; o_acc[df][1] = zf; }

    __syncthreads();                  // stage(0) landed for all waves

    for (int t = 0; t < N_ / 128; ++t) {
        const int cur = t & 1;
        if (t + 1 < N_ / 128) stage(t + 1, cur ^ 1);   // issue early, land late

        // ---- S^T(half) = K(half)·Q^T : 4 kv-frags x 4 d-ksteps ----
        f32x4 sacc[4][2];
        #pragma unroll
        for (int kvf = 0; kvf < 4; ++kvf) { sacc[kvf][0] = zf; sacc[kvf][1] = zf; }
        #pragma unroll
        for (int ks = 0; ks < 4; ++ks) {
            #pragma unroll
            for (int kvf = 0; kvf < 4; ++kvf) {
                const int row = kvh*64 + 16*kvf + cq;
                const short8 ak = *reinterpret_cast<const short8*>(
                    &Ks[cur][row * 128 + (((g + 4*ks) ^ (row & 15)) * 8)]);
                sacc[kvf][0] = __builtin_amdgcn_mfma_f32_16x16x32_bf16(
                    ak, qreg[0][ks], sacc[kvf][0], 0, 0, 0);
                sacc[kvf][1] = __builtin_amdgcn_mfma_f32_16x16x32_bf16(
                    ak, qreg[1][ks], sacc[kvf][1], 0, 0, 0);
            }
        }

        // ---- per-wave softmax (exp2 domain) + P publish + P-frag read ----
        short8 bp[2][2];
        #pragma unroll
        for (int qf = 0; qf < 2; ++qf) {
            float pmax = -3.0e38f;
            #pragma unroll
            for (int kvf = 0; kvf < 4; ++kvf)
                #pragma unroll
                for (int r = 0; r < 4; ++r)
                    pmax = fmaxf(pmax, sacc[kvf][qf][r]);
            pmax = fmaxf(pmax, __shfl_xor(pmax, 16));
            pmax = fmaxf(pmax, __shfl_xor(pmax, 32));

            if (__any(pmax > m_run[qf] + 8.f)) {       // defer-max, THR=8
                const float mnew = fmaxf(m_run[qf], pmax);
                const float corr = exp2f_fast(m_run[qf] - mnew);
                m_run[qf] = mnew;
                l_run[qf] *= corr;
                #pragma unroll
                for (int df = 0; df < 8; ++df)
                    #pragma unroll
                    for (int r = 0; r < 4; ++r)
                        o_acc[df][qf][r] *= corr;      // in-lane: cols = my q
            }

            float lsum = 0.f;
            #pragma unroll
            for (int kvf = 0; kvf < 4; ++kvf) {
                const float p0 = exp2f_fast(sacc[kvf][qf][0] - m_run[qf]);
                const float p1 = exp2f_fast(sacc[kvf][qf][1] - m_run[qf]);
                const float p2 = exp2f_fast(sacc[kvf][qf][2] - m_run[qf]);
                const float p3 = exp2f_fast(sacc[kvf][qf][3] - m_run[qf]);
                lsum += (p0 + p1) + (p2 + p3);
                // kv_local = 16*kvf + 4*g + r  ->  elem offset 16*kvf + 4*g
                *reinterpret_cast<uint2*>(&Ps[w][cq*80 + 16*kvf + 4*g]) =
                    make_uint2(cvt_pk_bf16(p0, p1), cvt_pk_bf16(p2, p3));
            }
            lsum += __shfl_xor(lsum, 16);
            lsum += __shfl_xor(lsum, 32);
            l_run[qf] += lsum;

            #pragma unroll
            for (int ks = 0; ks < 2; ++ks)             // P^T B-frags -> regs
                bp[qf][ks] = *reinterpret_cast<const short8*>(
                    &Ps[w][cq*80 + (4*ks + g) * 8]);
        }

        // ---- O^T(partial) += V^T(:,half) · P^T ----
        #pragma unroll
        for (int ks = 0; ks < 2; ++ks) {
            #pragma unroll
            for (int df = 0; df < 8; ++df) {
                const int row = 16*df + cq;
                const int ch  = kvh*8 + 4*ks + g;
                const short8 av = *reinterpret_cast<const short8*>(
                    &Vs[cur][row * 128 + ((ch ^ (row & 15)) * 8)]);
                o_acc[df][0] = __builtin_amdgcn_mfma_f32_16x16x32_bf16(
                    av, bp[0][ks], o_acc[df][0], 0, 0, 0);
                o_acc[df][1] = __builtin_amdgcn_mfma_f32_16x16x32_bf16(
                    av, bp[1][ks], o_acc[df][1], 0, 0, 0);
            }
        }
        __syncthreads();   // next tile staged + everyone done with buf cur
    }

    // ---- merge kv-halves (waves qb / qb+4) via LDS, then write ctx ----
    float* mbuf = reinterpret_cast<float*>(&Ks[0][0]);        // 256 floats
    float* lbuf = mbuf + 256;                                 // 256 floats
    f32x4* obuf = reinterpret_cast<f32x4*>(&Vs[0][0]);        // 4096 f32x4

    if (kvh == 1) {
        #pragma unroll
        for (int qf = 0; qf < 2; ++qf) {
            mbuf[(qb*2 + qf)*16 + cq] = m_run[qf];   // 4 g-dups, same value
            lbuf[(qb*2 + qf)*16 + cq] = l_run[qf];
        }
        #pragma unroll
        for (int df = 0; df < 8; ++df)
            #pragma unroll
            for (int qf = 0; qf < 2; ++qf)
                obuf[qb*1024 + (df*2 + qf)*64 + lane] = o_acc[df][qf];
    }
    __syncthreads();
    if (kvh == 0) {
        #pragma unroll
        for (int qf = 0; qf < 2; ++qf) {
            const float mB = mbuf[(qb*2 + qf)*16 + cq];
            const float lB = lbuf[(qb*2 + qf)*16 + cq];
            const float ms = fmaxf(m_run[qf], mB);
            const float cA = exp2f_fast(m_run[qf] - ms);
            const float cB = exp2f_fast(mB - ms);
            const float inv = 1.f / (l_run[qf] * cA + lB * cB);

            const int n = qt*128 + qb*32 + 16*qf + cq;
            uint16_t* dst = ctx + ((size_t)b * N_ + n) * C_ + h * D_;
            #pragma unroll
            for (int df = 0; df < 8; ++df) {
                const f32x4 oB = obuf[qb*1024 + (df*2 + qf)*64 + lane];
                float v0 = (o_acc[df][qf][0]*cA + oB[0]*cB) * inv;
                float v1 = (o_acc[df][qf][1]*cA + oB[1]*cB) * inv;
                float v2 = (o_acc[df][qf][2]*cA + oB[2]*cB) * inv;
                float v3 = (o_acc[df][qf][3]*cA + oB[3]*cB) * inv;
                const uint32_t w0 = (uint32_t)f2bf(v0) | ((uint32_t)f2bf(v1) << 16);
                const uint32_t w1 = (uint32_t)f2bf(v2) | ((uint32_t)f2bf(v3) << 16);
                *reinterpret_cast<uint2*>(&dst[16*df + 4*g]) = make_uint2(w0, w1);
            }
        }
    }
}

// ---------------------------------------------------------------------------
// Proj GEMM: out = ctx @ proj_w^T + bias, f32 out. Same staging as gemm_qkv.
// ---------------------------------------------------------------------------
__global__ __launch_bounds__(256, 2)
void gemm_proj(const uint16_t* __restrict__ A,   // ctx [8192][512]
               const uint16_t* __restrict__ Bw,  // pwb [512][512]
               const float* __restrict__ bias,   // [512]
               float* __restrict__ out)          // [8192][512] f32
{
    __shared__ __align__(16) uint16_t As[128 * 64];
    __shared__ __align__(16) uint16_t Bs[128 * 64];

    const int tid  = threadIdx.x;
    const int lane = tid & 63;
    const int w    = tid >> 6;
    const int wr   = w >> 1, wc = w & 1;
    const int cq   = lane & 15;
    const int g    = lane >> 4;
    const int m0   = blockIdx.x * 128;
    const int o0   = blockIdx.y * 128;

    f32x4 acc[4][4];
    const f32x4 zf = {0.f, 0.f, 0.f, 0.f};
    #pragma unroll
    for (int i = 0; i < 4; ++i)
        #pragma unroll
        for (int j = 0; j < 4; ++j) acc[i][j] = zf;

    for (int kt = 0; kt < C_; kt += 64) {
        __syncthreads();
        #pragma unroll
        for (int i = 0; i < 4; ++i) {
            int s = tid + 256 * i;
            int row = s >> 3, p = s & 7, c = p ^ (row & 7);
            load_lds16(A  + (size_t)(m0 + row) * C_ + kt + c * 8, &As[row*64 + p*8]);
            load_lds16(Bw + (size_t)(o0 + row) * C_ + kt + c * 8, &Bs[row*64 + p*8]);
        }
        __syncthreads();
        #pragma unroll
        for (int ks = 0; ks < 2; ++ks) {
            short8 af[4], bfr[4];
            #pragma unroll
            for (int mi = 0; mi < 4; ++mi) {
                int r = 64*wr + 16*mi + cq;
                af[mi] = *reinterpret_cast<const short8*>(
                    &As[r*64 + (((g + 4*ks) ^ (r & 7)) * 8)]);
            }
            #pragma unroll
            for (int ni = 0; ni < 4; ++ni) {
                int r = 64*wc + 16*ni + cq;
                bfr[ni] = *reinterpret_cast<const short8*>(
                    &Bs[r*64 + (((g + 4*ks) ^ (r & 7)) * 8)]);
            }
            #pragma unroll
            for (int mi = 0; mi < 4; ++mi)
                #pragma unroll
                for (int ni = 0; ni < 4; ++ni)
                    acc[mi][ni] = __builtin_amdgcn_mfma_f32_16x16x32_bf16(
                        af[mi], bfr[ni], acc[mi][ni], 0, 0, 0);
        }
    }

    #pragma unroll
    for (int ni = 0; ni < 4; ++ni) {
        const int o = o0 + 64*wc + 16*ni + cq;
        const float bv = bias[o];
        #pragma unroll
        for (int mi = 0; mi < 4; ++mi) {
            #pragma unroll
            for (int r = 0; r < 4; ++r) {
                const int m = m0 + 64*wr + 16*mi + 4*g + r;
                out[(size_t)m * C_ + o] = acc[mi][ni][r] + bv;
            }
        }
    }
}

// ---------------------------------------------------------------------------
extern "C" void kernel_launch(void* const* d_in, const int* in_sizes, int n_in,
                              void* d_out, int out_size, void* d_ws, size_t ws_size,
                              hipStream_t stream)
{
    const float* x      = (const float*)d_in[0];
    const float* qkv_w  = (const float*)d_in[1];
    const float* qkv_b  = (const float*)d_in[2];
    const float* proj_w = (const float*)d_in[3];
    const float* proj_b = (const float*)d_in[4];
    float* out = (float*)d_out;

    // ws layout (bf16 elems): xb | wb | pwb | Qb | Kb | Vt | ctx
    uint16_t* xb  = (uint16_t*)d_ws;
    uint16_t* wb  = xb  + (size_t)M_ * C_;           // 4194304
    uint16_t* pwb = wb  + (size_t)TC_ * C_;          //  786432
    uint16_t* Qb  = pwb + (size_t)C_ * C_;           //  262144
    uint16_t* Kb  = Qb  + (size_t)B_ * H_ * N_ * D_; // 4194304 each
    uint16_t* Vt  = Kb  + (size_t)B_ * H_ * N_ * D_;
    uint16_t* ctx = Vt  + (size_t)B_ * H_ * N_ * D_;

    cast3_kernel<<<2560, 256, 0, stream>>>(x, qkv_w, proj_w, xb, wb, pwb);
    gemm_qkv<<<dim3(M_/128, TC_/128), 256, 0, stream>>>(xb, wb, qkv_b, Qb, Kb, Vt);
    attn_kernel<<<(N_/128) * (B_*H_), 512, 0, stream>>>(Qb, Kb, Vt, ctx);
    gemm_proj<<<dim3(M_/128, C_/128), 256, 0, stream>>>(ctx, pwb, proj_b, out);
}